// Round 2
// baseline (864.915 us; speedup 1.0000x reference)
//
#include <hip/hip_runtime.h>
#include <hip/hip_bf16.h>

typedef __bf16 bf16;
typedef __bf16 bf16x8 __attribute__((ext_vector_type(8)));
typedef float f32x4 __attribute__((ext_vector_type(4)));

#define MFMA16(a, b, c) __builtin_amdgcn_mfma_f32_16x16x32_bf16((a), (b), (c), 0, 0, 0)

// Load 8 contiguous elements as bf16x8; fp32 sources are converted in-flight.
template <typename T>
__device__ __forceinline__ bf16x8 load8(const T* p) {
  if constexpr (sizeof(T) == 2) {
    return *reinterpret_cast<const bf16x8*>(p);
  } else {
    const float4 a = *reinterpret_cast<const float4*>(p);
    const float4 b = *reinterpret_cast<const float4*>(p + 4);
    bf16x8 r;
    r[0] = (bf16)a.x; r[1] = (bf16)a.y; r[2] = (bf16)a.z; r[3] = (bf16)a.w;
    r[4] = (bf16)b.x; r[5] = (bf16)b.y; r[6] = (bf16)b.z; r[7] = (bf16)b.w;
    return r;
  }
}

// C[M,N] = A[M,K] @ W[N,K]^T + bias[N]; bf16 MFMA, fp32 accum.
// 128x128 tile, BK=64, 4 waves (2x2), each wave 64x64 (4x4 frags of 16x16).
// Register staging (global -> cvt bf16 -> ds_write_b128 at XOR-swizzled slot);
// ds_read side uses the matching swizzle -> conflict-free b128 reads.
template <typename TA, typename TB, typename TC>
__global__ __launch_bounds__(256, 2) void gemm_bias_kernel(
    const TA* __restrict__ A, const TB* __restrict__ W,
    const float* __restrict__ bias, TC* __restrict__ C,
    int M, int N, int K, int nbc) {
  __shared__ bf16 Asm[128 * 64];
  __shared__ bf16 Bsm[128 * 64];
  const int tid = threadIdx.x;
  const int lane = tid & 63;
  const int wid = tid >> 6;
  const int l15 = lane & 15;
  const int l4 = lane >> 4;
  const int bid = blockIdx.x;
  const int brow = (bid / nbc) << 7;
  const int bcol = (bid % nbc) << 7;
  const int wm = (wid >> 1) << 6;
  const int wn = (wid & 1) << 6;

  f32x4 acc[4][4] = {};

  for (int k0 = 0; k0 < K; k0 += 64) {
    __syncthreads();
#pragma unroll
    for (int i = 0; i < 4; ++i) {
      const int c = i * 256 + tid;           // 8-elem chunk index, 1024 total
      const int row = c >> 3;                // tile row
      const int lin = c & 7;                 // linear k-chunk within row
      const int slot = lin ^ (row & 7);      // swizzled LDS slot
      *reinterpret_cast<bf16x8*>(Asm + row * 64 + slot * 8) =
          load8(A + (size_t)(brow + row) * K + k0 + lin * 8);
      *reinterpret_cast<bf16x8*>(Bsm + row * 64 + slot * 8) =
          load8(W + (size_t)(bcol + row) * K + k0 + lin * 8);
    }
    __syncthreads();
#pragma unroll
    for (int kk = 0; kk < 2; ++kk) {
      bf16x8 af[4], bfr[4];
#pragma unroll
      for (int m = 0; m < 4; ++m) {
        const int row = wm + m * 16 + l15;
        const int slot = (kk * 4 + l4) ^ (row & 7);
        af[m] = *reinterpret_cast<const bf16x8*>(Asm + row * 64 + slot * 8);
      }
#pragma unroll
      for (int n = 0; n < 4; ++n) {
        const int row = wn + n * 16 + l15;
        const int slot = (kk * 4 + l4) ^ (row & 7);
        bfr[n] = *reinterpret_cast<const bf16x8*>(Bsm + row * 64 + slot * 8);
      }
#pragma unroll
      for (int m = 0; m < 4; ++m)
#pragma unroll
        for (int n = 0; n < 4; ++n)
          acc[m][n] = MFMA16(af[m], bfr[n], acc[m][n]);
    }
  }

  // C/D layout: col = lane&15, row = (lane>>4)*4 + reg  [m89/m91 verified]
  const int r0 = brow + wm + l4 * 4;
  const int c0 = bcol + wn + l15;
#pragma unroll
  for (int n = 0; n < 4; ++n) {
    const float bv = bias[c0 + n * 16];
#pragma unroll
    for (int m = 0; m < 4; ++m) {
#pragma unroll
      for (int r = 0; r < 4; ++r) {
        C[(size_t)(r0 + m * 16 + r) * N + (c0 + n * 16)] =
            (TC)(acc[m][n][r] + bv);
      }
    }
  }
}

// Vt[(b*16+h)*64 + d][s] = V[(b*2048+s)*1024 + h*64 + d]   (bf16 -> bf16)
__global__ __launch_bounds__(256) void transpose_v_kernel(
    const bf16* __restrict__ V, bf16* __restrict__ Vt) {
  __shared__ unsigned short t[64][72];  // +8 pad
  const int bid = blockIdx.x;
  const int st = bid & 31;
  const int h = (bid >> 5) & 15;
  const int b = bid >> 9;
  const int s0 = st * 64;
  const int tid = threadIdx.x;
#pragma unroll
  for (int i = 0; i < 2; ++i) {
    const int c = i * 256 + tid;
    const int row = c >> 3;          // s within tile
    const int off = (c & 7) * 8;     // d offset
    const uint4 v = *reinterpret_cast<const uint4*>(
        &V[(size_t)(b * 2048 + s0 + row) * 1024 + h * 64 + off]);
    *reinterpret_cast<uint4*>(&t[row][off]) = v;
  }
  __syncthreads();
#pragma unroll
  for (int i = 0; i < 2; ++i) {
    const int c = i * 256 + tid;
    const int d = c >> 3;
    const int so = (c & 7) * 8;
    unsigned short tmp[8] __attribute__((aligned(16)));
#pragma unroll
    for (int j = 0; j < 8; ++j) tmp[j] = t[so + j][d];
    *reinterpret_cast<uint4*>(
        &Vt[(size_t)((b * 16 + h) * 64 + d) * 2048 + s0 + so]) =
        *reinterpret_cast<const uint4*>(tmp);
  }
}

// Flash attention. Block = (b, h, 64 q-rows); 4 waves x 16 q-rows.
// Q,K bf16 [B*S, H]; Vt bf16 [(b*16+h)*64+d][S]; mask fp32 [B,S,S].
// ctx may alias Q (each block writes exactly the region it already read).
__global__ __launch_bounds__(256) void attn_kernel(
    const bf16* __restrict__ Q, const bf16* __restrict__ Kt,
    const bf16* __restrict__ Vt, const float* __restrict__ mask,
    bf16* __restrict__ ctx) {
  __shared__ bf16 Pl[4][1024];  // per-wave 16x64 P tile, XOR-swizzled
  const int bid = blockIdx.x;
  const int qb = bid & 31;
  const int h = (bid >> 5) & 15;
  const int b = bid >> 9;
  const int tid = threadIdx.x;
  const int lane = tid & 63;
  const int wid = tid >> 6;
  const int l15 = lane & 15;
  const int l4 = lane >> 4;

  const int qbase = qb * 64 + wid * 16;  // s-index of this wave's first q row

  // Q fragments (A-operand): lane holds Q[qbase + (l&15)][kk*32 + (l>>4)*8 + j]
  bf16x8 qf[2];
#pragma unroll
  for (int kk = 0; kk < 2; ++kk)
    qf[kk] = *reinterpret_cast<const bf16x8*>(
        &Q[(size_t)(b * 2048 + qbase + l15) * 1024 + h * 64 + kk * 32 + l4 * 8]);

  f32x4 o[4] = {};        // o[dt]: rows q=(l>>4)*4+r, col d=dt*16+(l&15)
  float mrow[4], lrow[4];
#pragma unroll
  for (int r = 0; r < 4; ++r) { mrow[r] = -1e30f; lrow[r] = 0.f; }

  const float scale = 0.125f;  // 1/sqrt(64)
  const float LOG2E = 1.44269504088896f;

  const bf16* Kb = Kt + (size_t)b * 2048 * 1024 + h * 64;
  const bf16* Vb = Vt + (size_t)(b * 16 + h) * 64 * 2048;
  const float* Mb = mask + (size_t)b * 2048 * 2048;
  char* Pw = reinterpret_cast<char*>(&Pl[wid][0]);

  for (int k0 = 0; k0 < 2048; k0 += 64) {
    // S = Q K^T for 4 k-tiles of 16
    f32x4 sf[4] = {};
#pragma unroll
    for (int kt = 0; kt < 4; ++kt) {
#pragma unroll
      for (int kk = 0; kk < 2; ++kk) {
        const bf16x8 kf = *reinterpret_cast<const bf16x8*>(
            &Kb[(size_t)(k0 + kt * 16 + l15) * 1024 + kk * 32 + l4 * 8]);
        sf[kt] = MFMA16(qf[kk], kf, sf[kt]);
      }
    }
    // scale + additive mask; per-row max
    float sv[4][4];
    float rmax[4];
#pragma unroll
    for (int r = 0; r < 4; ++r) rmax[r] = -1e30f;
#pragma unroll
    for (int kt = 0; kt < 4; ++kt) {
#pragma unroll
      for (int r = 0; r < 4; ++r) {
        const int q = qbase + l4 * 4 + r;
        const int kg = k0 + kt * 16 + l15;
        const float x = sf[kt][r] * scale + Mb[(size_t)q * 2048 + kg];
        sv[kt][r] = x;
        rmax[r] = fmaxf(rmax[r], x);
      }
    }
#pragma unroll
    for (int off = 1; off < 16; off <<= 1)
#pragma unroll
      for (int r = 0; r < 4; ++r)
        rmax[r] = fmaxf(rmax[r], __shfl_xor(rmax[r], off, 64));
    float alpha[4], rsum[4] = {0.f, 0.f, 0.f, 0.f};
#pragma unroll
    for (int r = 0; r < 4; ++r) {
      const float mn = fmaxf(mrow[r], rmax[r]);
      alpha[r] = __builtin_exp2f((mrow[r] - mn) * LOG2E);
      mrow[r] = mn;
    }
    // P = exp(s - m) -> bf16 -> swizzled per-wave LDS (D-layout -> A-layout)
#pragma unroll
    for (int kt = 0; kt < 4; ++kt) {
#pragma unroll
      for (int r = 0; r < 4; ++r) {
        const float p = __builtin_exp2f((sv[kt][r] - mrow[r]) * LOG2E);
        rsum[r] += p;
        const int q = l4 * 4 + r;
        const int k = kt * 16 + l15;
        const int byteoff = (q << 7) + ((2 * k) ^ ((q & 7) << 4));
        *reinterpret_cast<bf16*>(Pw + byteoff) = (bf16)p;
      }
    }
#pragma unroll
    for (int off = 1; off < 16; off <<= 1)
#pragma unroll
      for (int r = 0; r < 4; ++r) rsum[r] += __shfl_xor(rsum[r], off, 64);
#pragma unroll
    for (int r = 0; r < 4; ++r) lrow[r] = lrow[r] * alpha[r] + rsum[r];
#pragma unroll
    for (int dt = 0; dt < 4; ++dt)
#pragma unroll
      for (int r = 0; r < 4; ++r) o[dt][r] *= alpha[r];
    // O += P V  (P as A-operand from LDS; V^T rows give contiguous B-frags)
#pragma unroll
    for (int kk = 0; kk < 2; ++kk) {
      const int kelem = kk * 32 + l4 * 8;
      const int byteoff = (l15 << 7) + ((2 * kelem) ^ ((l15 & 7) << 4));
      const bf16x8 pf = *reinterpret_cast<const bf16x8*>(Pw + byteoff);
#pragma unroll
      for (int dt = 0; dt < 4; ++dt) {
        const bf16x8 vf = *reinterpret_cast<const bf16x8*>(
            &Vb[(size_t)(dt * 16 + l15) * 2048 + k0 + kelem]);
        o[dt] = MFMA16(pf, vf, o[dt]);
      }
    }
  }
  // ctx = O / l
#pragma unroll
  for (int dt = 0; dt < 4; ++dt) {
#pragma unroll
    for (int r = 0; r < 4; ++r) {
      const int q = qbase + l4 * 4 + r;
      ctx[(size_t)(b * 2048 + q) * 1024 + h * 64 + dt * 16 + l15] =
          (bf16)(o[dt][r] / lrow[r]);
    }
  }
}

extern "C" void kernel_launch(void* const* d_in, const int* in_sizes, int n_in,
                              void* d_out, int out_size, void* d_ws,
                              size_t ws_size, hipStream_t stream) {
  const float* key = (const float*)d_in[0];
  const float* query = (const float*)d_in[1];
  const float* value = (const float*)d_in[2];
  const float* mask = (const float*)d_in[3];
  const float* wq = (const float*)d_in[4];
  const float* bq = (const float*)d_in[5];
  const float* wk = (const float*)d_in[6];
  const float* bk = (const float*)d_in[7];
  const float* wv = (const float*)d_in[8];
  const float* bv = (const float*)d_in[9];
  const float* wo = (const float*)d_in[10];
  const float* bo = (const float*)d_in[11];
  float* out = (float*)d_out;

  const size_t NBSH = (size_t)4 * 2048 * 1024;  // 8,388,608 elements
  bf16* Qws = (bf16*)d_ws;        // Q, later overwritten in place by ctx
  bf16* Kws = Qws + NBSH;
  bf16* Vt = Kws + NBSH;          // total ws use: 50.3 MB
  bf16* Vtmp = (bf16*)d_out;      // stage bf16 V projection in d_out (fits)

  const dim3 blk(256);
  gemm_bias_kernel<float, float, bf16>
      <<<512, blk, 0, stream>>>(query, wq, bq, Qws, 8192, 1024, 1024, 8);
  gemm_bias_kernel<float, float, bf16>
      <<<512, blk, 0, stream>>>(key, wk, bk, Kws, 8192, 1024, 1024, 8);
  gemm_bias_kernel<float, float, bf16>
      <<<512, blk, 0, stream>>>(value, wv, bv, Vtmp, 8192, 1024, 1024, 8);
  transpose_v_kernel<<<2048, blk, 0, stream>>>(Vtmp, Vt);
  attn_kernel<<<2048, blk, 0, stream>>>(Qws, Kws, Vt, mask, Qws);
  gemm_bias_kernel<bf16, float, float>
      <<<512, blk, 0, stream>>>(Qws, wo, bo, out, 8192, 1024, 1024, 8);
}

// Round 3
// 717.336 us; speedup vs baseline: 1.2057x; 1.2057x over previous
//
#include <hip/hip_runtime.h>
#include <hip/hip_bf16.h>

typedef __bf16 bf16;
typedef __bf16 bf16x8 __attribute__((ext_vector_type(8)));
typedef float f32x4 __attribute__((ext_vector_type(4)));

#define MFMA16(a, b, c) __builtin_amdgcn_mfma_f32_16x16x32_bf16((a), (b), (c), 0, 0, 0)

// XCD-chunked block swizzle (nblk % 8 == 0): each XCD gets a contiguous chunk.
__device__ __forceinline__ int xcd_swizzle(int bid, int nblk) {
  const int per = nblk >> 3;
  return (bid & 7) * per + (bid >> 3);
}

// ---------------- GEMM: C[M,N] = (A[M,K] @ W[N,K]^T + bias) * cscale --------
// 128x128 tile, BK=64, 4 waves (2x2). 2-phase pipeline: double-buffered LDS,
// next tile's global loads issued before computing current tile (1 barrier/tile).
template <typename T> struct StageRegs;
template <> struct StageRegs<float> { float4 lo[4], hi[4]; };
template <> struct StageRegs<bf16> { bf16x8 v[4]; };

template <typename T>
__device__ __forceinline__ void stage_issue(StageRegs<T>& r, const T* base,
                                            int rowstride, int brc, int k0,
                                            int tid) {
#pragma unroll
  for (int i = 0; i < 4; ++i) {
    const int c = i * 256 + tid;
    const int row = c >> 3, lin = c & 7;
    const T* p = base + (size_t)(brc + row) * rowstride + k0 + lin * 8;
    if constexpr (sizeof(T) == 4) {
      r.lo[i] = *reinterpret_cast<const float4*>(p);
      r.hi[i] = *reinterpret_cast<const float4*>(p + 4);
    } else {
      r.v[i] = *reinterpret_cast<const bf16x8*>(p);
    }
  }
}

template <typename T>
__device__ __forceinline__ void stage_write(const StageRegs<T>& r, bf16* sm,
                                            int tid) {
#pragma unroll
  for (int i = 0; i < 4; ++i) {
    const int c = i * 256 + tid;
    const int row = c >> 3, lin = c & 7;
    const int slot = lin ^ (row & 7);  // XOR swizzle -> conflict-free b128 reads
    bf16x8 v;
    if constexpr (sizeof(T) == 4) {
      const float4 a = r.lo[i], b = r.hi[i];
      v[0] = (bf16)a.x; v[1] = (bf16)a.y; v[2] = (bf16)a.z; v[3] = (bf16)a.w;
      v[4] = (bf16)b.x; v[5] = (bf16)b.y; v[6] = (bf16)b.z; v[7] = (bf16)b.w;
    } else {
      v = r.v[i];
    }
    *reinterpret_cast<bf16x8*>(sm + row * 64 + slot * 8) = v;
  }
}

template <typename TA, typename TB, typename TC>
__global__ __launch_bounds__(256, 2) void gemm_bias_kernel(
    const TA* __restrict__ A, const TB* __restrict__ W,
    const float* __restrict__ bias, TC* __restrict__ C, int M, int N, int K,
    int nbc, float cscale) {
  __shared__ bf16 Asm[2][128 * 64];
  __shared__ bf16 Bsm[2][128 * 64];
  const int tid = threadIdx.x;
  const int lane = tid & 63;
  const int wid = tid >> 6;
  const int l15 = lane & 15;
  const int l4 = lane >> 4;
  const int bid = xcd_swizzle(blockIdx.x, gridDim.x);
  const int brow = (bid / nbc) << 7;
  const int bcol = (bid % nbc) << 7;
  const int wm = (wid >> 1) << 6;
  const int wn = (wid & 1) << 6;

  f32x4 acc[4][4] = {};

  StageRegs<TA> ra;
  StageRegs<TB> rb;
  stage_issue(ra, A, K, brow, 0, tid);
  stage_issue(rb, W, K, bcol, 0, tid);

  const int nt = K >> 6;
  int p = 0;
  for (int t = 0; t < nt; ++t) {
    stage_write(ra, Asm[p], tid);
    stage_write(rb, Bsm[p], tid);
    if (t + 1 < nt) {
      stage_issue(ra, A, K, brow, (t + 1) << 6, tid);
      stage_issue(rb, W, K, bcol, (t + 1) << 6, tid);
    }
    __syncthreads();
#pragma unroll
    for (int kk = 0; kk < 2; ++kk) {
      bf16x8 af[4], bfr[4];
#pragma unroll
      for (int m = 0; m < 4; ++m) {
        const int row = wm + m * 16 + l15;
        const int slot = (kk * 4 + l4) ^ (row & 7);
        af[m] = *reinterpret_cast<const bf16x8*>(Asm[p] + row * 64 + slot * 8);
      }
#pragma unroll
      for (int n = 0; n < 4; ++n) {
        const int row = wn + n * 16 + l15;
        const int slot = (kk * 4 + l4) ^ (row & 7);
        bfr[n] = *reinterpret_cast<const bf16x8*>(Bsm[p] + row * 64 + slot * 8);
      }
      __builtin_amdgcn_s_setprio(1);
#pragma unroll
      for (int m = 0; m < 4; ++m)
#pragma unroll
        for (int n = 0; n < 4; ++n)
          acc[m][n] = MFMA16(af[m], bfr[n], acc[m][n]);
      __builtin_amdgcn_s_setprio(0);
    }
    p ^= 1;
  }

  // C/D layout: col = lane&15, row = (lane>>4)*4 + reg
  const int r0 = brow + wm + l4 * 4;
  const int c0 = bcol + wn + l15;
#pragma unroll
  for (int n = 0; n < 4; ++n) {
    const float bv = bias[c0 + n * 16];
#pragma unroll
    for (int m = 0; m < 4; ++m) {
#pragma unroll
      for (int r = 0; r < 4; ++r) {
        C[(size_t)(r0 + m * 16 + r) * N + (c0 + n * 16)] =
            (TC)((acc[m][n][r] + bv) * cscale);
      }
    }
  }
}

// Vt[(b*16+h)*64 + d][s] = V[(b*2048+s)*1024 + h*64 + d]   (bf16 -> bf16)
__global__ __launch_bounds__(256) void transpose_v_kernel(
    const bf16* __restrict__ V, bf16* __restrict__ Vt) {
  __shared__ unsigned short t[64][72];
  const int bid = blockIdx.x;
  const int st = bid & 31;
  const int h = (bid >> 5) & 15;
  const int b = bid >> 9;
  const int s0 = st * 64;
  const int tid = threadIdx.x;
#pragma unroll
  for (int i = 0; i < 2; ++i) {
    const int c = i * 256 + tid;
    const int row = c >> 3;
    const int off = (c & 7) * 8;
    const uint4 v = *reinterpret_cast<const uint4*>(
        &V[(size_t)(b * 2048 + s0 + row) * 1024 + h * 64 + off]);
    *reinterpret_cast<uint4*>(&t[row][off]) = v;
  }
  __syncthreads();
#pragma unroll
  for (int i = 0; i < 2; ++i) {
    const int c = i * 256 + tid;
    const int d = c >> 3;
    const int so = (c & 7) * 8;
    unsigned short tmp[8] __attribute__((aligned(16)));
#pragma unroll
    for (int j = 0; j < 8; ++j) tmp[j] = t[so + j][d];
    *reinterpret_cast<uint4*>(
        &Vt[(size_t)((b * 16 + h) * 64 + d) * 2048 + s0 + so]) =
        *reinterpret_cast<const uint4*>(tmp);
  }
}

// ---------------- Flash attention, software-pipelined ----------------------
// Block = (b, h, 64 q-rows); 4 independent waves x 16 q-rows (no barriers).
// Q pre-scaled by 1/8 in projection. Per tile: prefetch next K frags + next
// mask (regs), early-issue current V frags; mask staged per-wave in LDS.
__global__ __launch_bounds__(256, 2) void attn_kernel(
    const bf16* __restrict__ Q, const bf16* __restrict__ Kt,
    const bf16* __restrict__ Vt, const float* __restrict__ mask,
    bf16* __restrict__ ctx) {
  __shared__ bf16 Pl[4][1024];        // per-wave 16x64 P tile, XOR-swizzled
  __shared__ float Ml[4][16 * 68];    // per-wave 16x64 mask tile, stride 68
  const int lid = xcd_swizzle(blockIdx.x, 2048);
  const int qb = lid & 31;
  const int h = (lid >> 5) & 15;
  const int b = lid >> 9;
  const int tid = threadIdx.x;
  const int lane = tid & 63;
  const int wid = tid >> 6;
  const int l15 = lane & 15;
  const int l4 = lane >> 4;

  const int qbase = qb * 64 + wid * 16;

  bf16x8 qf[2];
#pragma unroll
  for (int kk = 0; kk < 2; ++kk)
    qf[kk] = *reinterpret_cast<const bf16x8*>(
        &Q[(size_t)(b * 2048 + qbase + l15) * 1024 + h * 64 + kk * 32 + l4 * 8]);

  f32x4 o[4] = {};
  float mrow[4], lrow[4];
#pragma unroll
  for (int r = 0; r < 4; ++r) { mrow[r] = -1e30f; lrow[r] = 0.f; }

  const float LOG2E = 1.44269504088896f;
  const bf16* Kb = Kt + (size_t)b * 2048 * 1024 + h * 64;
  const bf16* Vb = Vt + (size_t)(b * 16 + h) * 64 * 2048;
  const float* Mb = mask + (size_t)b * 2048 * 2048;
  char* Pw = reinterpret_cast<char*>(&Pl[wid][0]);
  float* Mw = &Ml[wid][0];

  bf16x8 kfA[4][2], kfB[4][2];
  float4 mreg[4];

  auto load_kf = [&](bf16x8(&kf)[4][2], int k0) {
#pragma unroll
    for (int kt = 0; kt < 4; ++kt)
#pragma unroll
      for (int kk = 0; kk < 2; ++kk)
        kf[kt][kk] = *reinterpret_cast<const bf16x8*>(
            &Kb[(size_t)(k0 + kt * 16 + l15) * 1024 + kk * 32 + l4 * 8]);
  };
  auto load_mask = [&](int k0) {
#pragma unroll
    for (int i = 0; i < 4; ++i) {
      const int c = i * 64 + lane;
      mreg[i] = *reinterpret_cast<const float4*>(
          &Mb[(size_t)(qbase + (c >> 4)) * 2048 + k0 + (c & 15) * 4]);
    }
  };
  auto store_mask = [&]() {
#pragma unroll
    for (int i = 0; i < 4; ++i) {
      const int c = i * 64 + lane;
      *reinterpret_cast<float4*>(&Mw[(c >> 4) * 68 + (c & 15) * 4]) = mreg[i];
    }
  };

  // Prologue: tile 0's K frags + mask.
  load_kf(kfA, 0);
  load_mask(0);
  store_mask();

  auto tile = [&](bf16x8(&kfc)[4][2], bf16x8(&kfn)[4][2], int k0) {
    int k0n = k0 + 64;
    if (k0n > 2048 - 64) k0n = 2048 - 64;  // clamp (redundant last reload)

    // Early-issue current V frags; prefetch next K frags + next mask.
    bf16x8 vf[4][2];
#pragma unroll
    for (int dt = 0; dt < 4; ++dt)
#pragma unroll
      for (int kk = 0; kk < 2; ++kk)
        vf[dt][kk] = *reinterpret_cast<const bf16x8*>(
            &Vb[(size_t)(dt * 16 + l15) * 2048 + k0 + kk * 32 + l4 * 8]);
    load_kf(kfn, k0n);
    load_mask(k0n);

    // QK^T (Q pre-scaled by 1/8)
    f32x4 sf[4] = {};
    __builtin_amdgcn_s_setprio(1);
#pragma unroll
    for (int kt = 0; kt < 4; ++kt)
#pragma unroll
      for (int kk = 0; kk < 2; ++kk)
        sf[kt] = MFMA16(qf[kk], kfc[kt][kk], sf[kt]);
    __builtin_amdgcn_s_setprio(0);

    // softmax (mask from per-wave LDS, current tile)
    float rmax[4];
#pragma unroll
    for (int r = 0; r < 4; ++r) rmax[r] = -1e30f;
#pragma unroll
    for (int kt = 0; kt < 4; ++kt) {
#pragma unroll
      for (int r = 0; r < 4; ++r) {
        const float x =
            sf[kt][r] + Mw[(l4 * 4 + r) * 68 + kt * 16 + l15];
        sf[kt][r] = x;
        rmax[r] = fmaxf(rmax[r], x);
      }
    }
#pragma unroll
    for (int off = 1; off < 16; off <<= 1)
#pragma unroll
      for (int r = 0; r < 4; ++r)
        rmax[r] = fmaxf(rmax[r], __shfl_xor(rmax[r], off, 64));
    float alpha[4], rsum[4] = {0.f, 0.f, 0.f, 0.f};
#pragma unroll
    for (int r = 0; r < 4; ++r) {
      const float mn = fmaxf(mrow[r], rmax[r]);
      alpha[r] = __builtin_exp2f((mrow[r] - mn) * LOG2E);
      mrow[r] = mn;
    }
#pragma unroll
    for (int kt = 0; kt < 4; ++kt) {
#pragma unroll
      for (int r = 0; r < 4; ++r) {
        const float pv = __builtin_exp2f((sf[kt][r] - mrow[r]) * LOG2E);
        rsum[r] += pv;
        const int q = l4 * 4 + r;
        const int k = kt * 16 + l15;
        const int byteoff = (q << 7) + ((2 * k) ^ ((q & 7) << 4));
        *reinterpret_cast<bf16*>(Pw + byteoff) = (bf16)pv;
      }
    }
#pragma unroll
    for (int off = 1; off < 16; off <<= 1)
#pragma unroll
      for (int r = 0; r < 4; ++r) rsum[r] += __shfl_xor(rsum[r], off, 64);
#pragma unroll
    for (int r = 0; r < 4; ++r) lrow[r] = lrow[r] * alpha[r] + rsum[r];
#pragma unroll
    for (int dt = 0; dt < 4; ++dt)
#pragma unroll
      for (int r = 0; r < 4; ++r) o[dt][r] *= alpha[r];

    // Park next tile's mask into LDS (after all current-tile mask reads;
    // per-wave DS ops complete in program order).
    store_mask();

    // O += P V
#pragma unroll
    for (int kk = 0; kk < 2; ++kk) {
      const int kelem = kk * 32 + l4 * 8;
      const int byteoff = (l15 << 7) + ((2 * kelem) ^ ((l15 & 7) << 4));
      const bf16x8 pf = *reinterpret_cast<const bf16x8*>(Pw + byteoff);
      __builtin_amdgcn_s_setprio(1);
#pragma unroll
      for (int dt = 0; dt < 4; ++dt)
        o[dt] = MFMA16(pf, vf[dt][kk], o[dt]);
      __builtin_amdgcn_s_setprio(0);
    }
  };

  for (int k0 = 0; k0 < 2048; k0 += 128) {
    tile(kfA, kfB, k0);
    tile(kfB, kfA, k0 + 64);
  }

#pragma unroll
  for (int dt = 0; dt < 4; ++dt) {
#pragma unroll
    for (int r = 0; r < 4; ++r) {
      const int q = qbase + l4 * 4 + r;
      ctx[(size_t)(b * 2048 + q) * 1024 + h * 64 + dt * 16 + l15] =
          (bf16)(o[dt][r] / lrow[r]);
    }
  }
}

extern "C" void kernel_launch(void* const* d_in, const int* in_sizes, int n_in,
                              void* d_out, int out_size, void* d_ws,
                              size_t ws_size, hipStream_t stream) {
  const float* key = (const float*)d_in[0];
  const float* query = (const float*)d_in[1];
  const float* value = (const float*)d_in[2];
  const float* mask = (const float*)d_in[3];
  const float* wq = (const float*)d_in[4];
  const float* bq = (const float*)d_in[5];
  const float* wk = (const float*)d_in[6];
  const float* bk = (const float*)d_in[7];
  const float* wv = (const float*)d_in[8];
  const float* bv = (const float*)d_in[9];
  const float* wo = (const float*)d_in[10];
  const float* bo = (const float*)d_in[11];
  float* out = (float*)d_out;

  const size_t NBSH = (size_t)4 * 2048 * 1024;
  bf16* Qws = (bf16*)d_ws;   // Q (pre-scaled by 1/8), later ctx in place
  bf16* Kws = Qws + NBSH;
  bf16* Vt = Kws + NBSH;     // total ws use: 50.3 MB
  bf16* Vtmp = (bf16*)d_out; // stage bf16 V projection in d_out

  const dim3 blk(256);
  gemm_bias_kernel<float, float, bf16><<<512, blk, 0, stream>>>(
      query, wq, bq, Qws, 8192, 1024, 1024, 8, 0.125f);
  gemm_bias_kernel<float, float, bf16><<<512, blk, 0, stream>>>(
      key, wk, bk, Kws, 8192, 1024, 1024, 8, 1.0f);
  gemm_bias_kernel<float, float, bf16><<<512, blk, 0, stream>>>(
      value, wv, bv, Vtmp, 8192, 1024, 1024, 8, 1.0f);
  transpose_v_kernel<<<2048, blk, 0, stream>>>(Vtmp, Vt);
  attn_kernel<<<2048, blk, 0, stream>>>(Qws, Kws, Vt, mask, Qws);
  gemm_bias_kernel<bf16, float, float><<<512, blk, 0, stream>>>(
      Qws, wo, bo, out, 8192, 1024, 1024, 8, 1.0f);
}

// Round 4
// 349.354 us; speedup vs baseline: 2.4758x; 2.0533x over previous
//
#include <hip/hip_runtime.h>
#include <hip/hip_bf16.h>

typedef __bf16 bf16;
typedef __bf16 bf16x8 __attribute__((ext_vector_type(8)));
typedef float f32x4 __attribute__((ext_vector_type(4)));

#define MFMA16(a, b, c) __builtin_amdgcn_mfma_f32_16x16x32_bf16((a), (b), (c), 0, 0, 0)

// XCD-chunked block swizzle (nblk % 8 == 0): each XCD gets a contiguous chunk.
__device__ __forceinline__ int xcd_swizzle(int bid, int nblk) {
  const int per = nblk >> 3;
  return (bid & 7) * per + (bid >> 3);
}

__device__ __forceinline__ void gload_lds16(const bf16* g, bf16* lds) {
  __builtin_amdgcn_global_load_lds(
      (const __attribute__((address_space(1))) void*)g,
      (__attribute__((address_space(3))) void*)lds, 16, 0, 0);
}

// ---------------- GEMM: C[M,N] = (A[M,K] @ W[N,K]^T + bias) * cscale --------
// (unchanged from round 3 — measured ~84us for all 4 GEMMs + transpose)
template <typename T> struct StageRegs;
template <> struct StageRegs<float> { float4 lo[4], hi[4]; };
template <> struct StageRegs<bf16> { bf16x8 v[4]; };

template <typename T>
__device__ __forceinline__ void stage_issue(StageRegs<T>& r, const T* base,
                                            int rowstride, int brc, int k0,
                                            int tid) {
#pragma unroll
  for (int i = 0; i < 4; ++i) {
    const int c = i * 256 + tid;
    const int row = c >> 3, lin = c & 7;
    const T* p = base + (size_t)(brc + row) * rowstride + k0 + lin * 8;
    if constexpr (sizeof(T) == 4) {
      r.lo[i] = *reinterpret_cast<const float4*>(p);
      r.hi[i] = *reinterpret_cast<const float4*>(p + 4);
    } else {
      r.v[i] = *reinterpret_cast<const bf16x8*>(p);
    }
  }
}

template <typename T>
__device__ __forceinline__ void stage_write(const StageRegs<T>& r, bf16* sm,
                                            int tid) {
#pragma unroll
  for (int i = 0; i < 4; ++i) {
    const int c = i * 256 + tid;
    const int row = c >> 3, lin = c & 7;
    const int slot = lin ^ (row & 7);
    bf16x8 v;
    if constexpr (sizeof(T) == 4) {
      const float4 a = r.lo[i], b = r.hi[i];
      v[0] = (bf16)a.x; v[1] = (bf16)a.y; v[2] = (bf16)a.z; v[3] = (bf16)a.w;
      v[4] = (bf16)b.x; v[5] = (bf16)b.y; v[6] = (bf16)b.z; v[7] = (bf16)b.w;
    } else {
      v = r.v[i];
    }
    *reinterpret_cast<bf16x8*>(sm + row * 64 + slot * 8) = v;
  }
}

template <typename TA, typename TB, typename TC>
__global__ __launch_bounds__(256, 2) void gemm_bias_kernel(
    const TA* __restrict__ A, const TB* __restrict__ W,
    const float* __restrict__ bias, TC* __restrict__ C, int M, int N, int K,
    int nbc, float cscale) {
  __shared__ bf16 Asm[2][128 * 64];
  __shared__ bf16 Bsm[2][128 * 64];
  const int tid = threadIdx.x;
  const int lane = tid & 63;
  const int wid = tid >> 6;
  const int l15 = lane & 15;
  const int l4 = lane >> 4;
  const int bid = xcd_swizzle(blockIdx.x, gridDim.x);
  const int brow = (bid / nbc) << 7;
  const int bcol = (bid % nbc) << 7;
  const int wm = (wid >> 1) << 6;
  const int wn = (wid & 1) << 6;

  f32x4 acc[4][4] = {};

  StageRegs<TA> ra;
  StageRegs<TB> rb;
  stage_issue(ra, A, K, brow, 0, tid);
  stage_issue(rb, W, K, bcol, 0, tid);

  const int nt = K >> 6;
  int p = 0;
  for (int t = 0; t < nt; ++t) {
    stage_write(ra, Asm[p], tid);
    stage_write(rb, Bsm[p], tid);
    if (t + 1 < nt) {
      stage_issue(ra, A, K, brow, (t + 1) << 6, tid);
      stage_issue(rb, W, K, bcol, (t + 1) << 6, tid);
    }
    __syncthreads();
#pragma unroll
    for (int kk = 0; kk < 2; ++kk) {
      bf16x8 af[4], bfr[4];
#pragma unroll
      for (int m = 0; m < 4; ++m) {
        const int row = wm + m * 16 + l15;
        const int slot = (kk * 4 + l4) ^ (row & 7);
        af[m] = *reinterpret_cast<const bf16x8*>(Asm[p] + row * 64 + slot * 8);
      }
#pragma unroll
      for (int n = 0; n < 4; ++n) {
        const int row = wn + n * 16 + l15;
        const int slot = (kk * 4 + l4) ^ (row & 7);
        bfr[n] = *reinterpret_cast<const bf16x8*>(Bsm[p] + row * 64 + slot * 8);
      }
      __builtin_amdgcn_s_setprio(1);
#pragma unroll
      for (int m = 0; m < 4; ++m)
#pragma unroll
        for (int n = 0; n < 4; ++n)
          acc[m][n] = MFMA16(af[m], bfr[n], acc[m][n]);
      __builtin_amdgcn_s_setprio(0);
    }
    p ^= 1;
  }

  const int r0 = brow + wm + l4 * 4;
  const int c0 = bcol + wn + l15;
#pragma unroll
  for (int n = 0; n < 4; ++n) {
    const float bv = bias[c0 + n * 16];
#pragma unroll
    for (int m = 0; m < 4; ++m) {
#pragma unroll
      for (int r = 0; r < 4; ++r) {
        C[(size_t)(r0 + m * 16 + r) * N + (c0 + n * 16)] =
            (TC)((acc[m][n][r] + bv) * cscale);
      }
    }
  }
}

// Vt[(b*16+h)*64 + d][s] = V[(b*2048+s)*1024 + h*64 + d]   (bf16 -> bf16)
__global__ __launch_bounds__(256) void transpose_v_kernel(
    const bf16* __restrict__ V, bf16* __restrict__ Vt) {
  __shared__ unsigned short t[64][72];
  const int bid = blockIdx.x;
  const int st = bid & 31;
  const int h = (bid >> 5) & 15;
  const int b = bid >> 9;
  const int s0 = st * 64;
  const int tid = threadIdx.x;
#pragma unroll
  for (int i = 0; i < 2; ++i) {
    const int c = i * 256 + tid;
    const int row = c >> 3;
    const int off = (c & 7) * 8;
    const uint4 v = *reinterpret_cast<const uint4*>(
        &V[(size_t)(b * 2048 + s0 + row) * 1024 + h * 64 + off]);
    *reinterpret_cast<uint4*>(&t[row][off]) = v;
  }
  __syncthreads();
#pragma unroll
  for (int i = 0; i < 2; ++i) {
    const int c = i * 256 + tid;
    const int d = c >> 3;
    const int so = (c & 7) * 8;
    unsigned short tmp[8] __attribute__((aligned(16)));
#pragma unroll
    for (int j = 0; j < 8; ++j) tmp[j] = t[so + j][d];
    *reinterpret_cast<uint4*>(
        &Vt[(size_t)((b * 16 + h) * 64 + d) * 2048 + s0 + so]) =
        *reinterpret_cast<const uint4*>(tmp);
  }
}

// ---------------- Flash attention, LDS-staged 2-phase ----------------------
// Block = (b, h, 64 q-rows); h varies FASTEST across blocks (+XCD chunking) so
// the 16 heads sharing one fp32 mask tile run back-to-back on one XCD -> L2 hit.
// Per k-tile (64): K(64x64) and Vt(64x64) cooperatively staged into LDS via
// global_load_lds (pre-swizzled source, linear dest), double-buffered, one
// barrier/tile; next tile's loads fly during current tile's compute. Mask in
// 16 dword regs, loaded one tile ahead right after consumption.
__global__ __launch_bounds__(256, 4) void attn_kernel(
    const bf16* __restrict__ Q, const bf16* __restrict__ Kt,
    const bf16* __restrict__ Vt, const float* __restrict__ mask,
    bf16* __restrict__ ctx) {
  __shared__ bf16 Ksm[2][64 * 64];
  __shared__ bf16 Vsm[2][64 * 64];
  __shared__ bf16 Pl[4][1024];  // per-wave 16x64 P tile, XOR-swizzled
  const int lid = xcd_swizzle(blockIdx.x, 2048);
  const int h = lid & 15;
  const int qb = (lid >> 4) & 31;
  const int b = lid >> 9;
  const int tid = threadIdx.x;
  const int lane = tid & 63;
  const int wid = tid >> 6;
  const int l15 = lane & 15;
  const int l4 = lane >> 4;

  const int qbase = qb * 64 + wid * 16;

  bf16x8 qf[2];
#pragma unroll
  for (int kk = 0; kk < 2; ++kk)
    qf[kk] = *reinterpret_cast<const bf16x8*>(
        &Q[(size_t)(b * 2048 + qbase + l15) * 1024 + h * 64 + kk * 32 + l4 * 8]);

  f32x4 o[4] = {};
  float mrow[4], lrow[4];
#pragma unroll
  for (int r = 0; r < 4; ++r) { mrow[r] = -1e30f; lrow[r] = 0.f; }

  const float LOG2E = 1.44269504088896f;
  const bf16* Kb = Kt + (size_t)b * 2048 * 1024 + h * 64;
  const bf16* Vb = Vt + (size_t)(b * 16 + h) * 64 * 2048;
  const float* Mb = mask + (size_t)b * 2048 * 2048;
  char* Pw = reinterpret_cast<char*>(&Pl[wid][0]);

  float mreg[4][4];  // [kt][r], current tile's mask values

  // Stage K-tile and Vt-tile for k-range [k0, k0+64) into buffer p.
  // 512 16B-chunks each; 256 threads x 2. Linear LDS dest (wave-uniform base
  // + lane*16), XOR-swizzled global source -> swizzled ds_read_b128 later.
  auto stage = [&](int p, int k0) {
#pragma unroll
    for (int i = 0; i < 2; ++i) {
      const int c = i * 256 + tid;
      const int row = c >> 3;
      const int lin = (c & 7) ^ (row & 7);  // pre-swizzled source chunk
      gload_lds16(Kb + (size_t)(k0 + row) * 1024 + lin * 8, &Ksm[p][c * 8]);
      gload_lds16(Vb + (size_t)row * 2048 + k0 + lin * 8, &Vsm[p][c * 8]);
    }
  };
  auto load_mask = [&](int k0) {
#pragma unroll
    for (int kt = 0; kt < 4; ++kt)
#pragma unroll
      for (int r = 0; r < 4; ++r)
        mreg[kt][r] =
            Mb[(size_t)(qbase + l4 * 4 + r) * 2048 + k0 + kt * 16 + l15];
  };

  stage(0, 0);
  load_mask(0);
  asm volatile("s_waitcnt vmcnt(0)" ::: "memory");
  __syncthreads();

  int p = 0;
  for (int t = 0; t < 32; ++t) {
    const int k0 = t << 6;
    if (t + 1 < 32) stage(p ^ 1, k0 + 64);  // in flight during compute

    // QK^T from LDS (Q pre-scaled by 1/8 in projection)
    f32x4 sf[4] = {};
    __builtin_amdgcn_s_setprio(1);
#pragma unroll
    for (int kt = 0; kt < 4; ++kt) {
#pragma unroll
      for (int kk = 0; kk < 2; ++kk) {
        const int row = kt * 16 + l15;
        const int slot = (kk * 4 + l4) ^ (row & 7);
        const bf16x8 kf =
            *reinterpret_cast<const bf16x8*>(&Ksm[p][row * 64 + slot * 8]);
        sf[kt] = MFMA16(qf[kk], kf, sf[kt]);
      }
    }
    __builtin_amdgcn_s_setprio(0);

    // add mask (regs), track row max
    float rmax[4];
#pragma unroll
    for (int r = 0; r < 4; ++r) rmax[r] = -1e30f;
#pragma unroll
    for (int kt = 0; kt < 4; ++kt) {
#pragma unroll
      for (int r = 0; r < 4; ++r) {
        const float x = sf[kt][r] + mreg[kt][r];
        sf[kt][r] = x;
        rmax[r] = fmaxf(rmax[r], x);
      }
    }
    if (t + 1 < 32) load_mask(k0 + 64);  // prefetch next mask (regs now free)

#pragma unroll
    for (int off = 1; off < 16; off <<= 1)
#pragma unroll
      for (int r = 0; r < 4; ++r)
        rmax[r] = fmaxf(rmax[r], __shfl_xor(rmax[r], off, 64));
    float alpha[4], rsum[4] = {0.f, 0.f, 0.f, 0.f};
#pragma unroll
    for (int r = 0; r < 4; ++r) {
      const float mn = fmaxf(mrow[r], rmax[r]);
      alpha[r] = __builtin_exp2f((mrow[r] - mn) * LOG2E);
      mrow[r] = mn;
    }
#pragma unroll
    for (int kt = 0; kt < 4; ++kt) {
#pragma unroll
      for (int r = 0; r < 4; ++r) {
        const float pv = __builtin_exp2f((sf[kt][r] - mrow[r]) * LOG2E);
        rsum[r] += pv;
        const int q = l4 * 4 + r;
        const int k = kt * 16 + l15;
        const int byteoff = (q << 7) + ((2 * k) ^ ((q & 7) << 4));
        *reinterpret_cast<bf16*>(Pw + byteoff) = (bf16)pv;
      }
    }
#pragma unroll
    for (int off = 1; off < 16; off <<= 1)
#pragma unroll
      for (int r = 0; r < 4; ++r) rsum[r] += __shfl_xor(rsum[r], off, 64);
#pragma unroll
    for (int r = 0; r < 4; ++r) lrow[r] = lrow[r] * alpha[r] + rsum[r];
#pragma unroll
    for (int dt = 0; dt < 4; ++dt)
#pragma unroll
      for (int r = 0; r < 4; ++r) o[dt][r] *= alpha[r];

    // O += P V  (P from per-wave LDS; V frags from staged LDS tile)
#pragma unroll
    for (int kk = 0; kk < 2; ++kk) {
      const int kelem = kk * 32 + l4 * 8;
      const int byteoff = (l15 << 7) + ((2 * kelem) ^ ((l15 & 7) << 4));
      const bf16x8 pf = *reinterpret_cast<const bf16x8*>(Pw + byteoff);
      __builtin_amdgcn_s_setprio(1);
#pragma unroll
      for (int dt = 0; dt < 4; ++dt) {
        const int row = dt * 16 + l15;
        const int slot = (kk * 4 + l4) ^ (row & 7);
        const bf16x8 vf =
            *reinterpret_cast<const bf16x8*>(&Vsm[p][row * 64 + slot * 8]);
        o[dt] = MFMA16(pf, vf, o[dt]);
      }
      __builtin_amdgcn_s_setprio(0);
    }

    asm volatile("s_waitcnt vmcnt(0)" ::: "memory");
    __syncthreads();
    p ^= 1;
  }

#pragma unroll
  for (int dt = 0; dt < 4; ++dt) {
#pragma unroll
    for (int r = 0; r < 4; ++r) {
      const int q = qbase + l4 * 4 + r;
      ctx[(size_t)(b * 2048 + q) * 1024 + h * 64 + dt * 16 + l15] =
          (bf16)(o[dt][r] / lrow[r]);
    }
  }
}

extern "C" void kernel_launch(void* const* d_in, const int* in_sizes, int n_in,
                              void* d_out, int out_size, void* d_ws,
                              size_t ws_size, hipStream_t stream) {
  const float* key = (const float*)d_in[0];
  const float* query = (const float*)d_in[1];
  const float* value = (const float*)d_in[2];
  const float* mask = (const float*)d_in[3];
  const float* wq = (const float*)d_in[4];
  const float* bq = (const float*)d_in[5];
  const float* wk = (const float*)d_in[6];
  const float* bk = (const float*)d_in[7];
  const float* wv = (const float*)d_in[8];
  const float* bv = (const float*)d_in[9];
  const float* wo = (const float*)d_in[10];
  const float* bo = (const float*)d_in[11];
  float* out = (float*)d_out;

  const size_t NBSH = (size_t)4 * 2048 * 1024;
  bf16* Qws = (bf16*)d_ws;   // Q (pre-scaled by 1/8), later ctx in place
  bf16* Kws = Qws + NBSH;
  bf16* Vt = Kws + NBSH;     // total ws use: 50.3 MB
  bf16* Vtmp = (bf16*)d_out; // stage bf16 V projection in d_out

  const dim3 blk(256);
  gemm_bias_kernel<float, float, bf16><<<512, blk, 0, stream>>>(
      query, wq, bq, Qws, 8192, 1024, 1024, 8, 0.125f);
  gemm_bias_kernel<float, float, bf16><<<512, blk, 0, stream>>>(
      key, wk, bk, Kws, 8192, 1024, 1024, 8, 1.0f);
  gemm_bias_kernel<float, float, bf16><<<512, blk, 0, stream>>>(
      value, wv, bv, Vtmp, 8192, 1024, 1024, 8, 1.0f);
  transpose_v_kernel<<<2048, blk, 0, stream>>>(Vtmp, Vt);
  attn_kernel<<<2048, blk, 0, stream>>>(Qws, Kws, Vt, mask, Qws);
  gemm_bias_kernel<bf16, float, float><<<512, blk, 0, stream>>>(
      Qws, wo, bo, out, 8192, 1024, 1024, 8, 1.0f);
}

// Round 5
// 323.029 us; speedup vs baseline: 2.6775x; 1.0815x over previous
//
#include <hip/hip_runtime.h>
#include <hip/hip_bf16.h>

typedef __bf16 bf16;
typedef __bf16 bf16x4 __attribute__((ext_vector_type(4)));
typedef __bf16 bf16x8 __attribute__((ext_vector_type(8)));
typedef float f32x4 __attribute__((ext_vector_type(4)));

#define MFMA16(a, b, c) __builtin_amdgcn_mfma_f32_16x16x32_bf16((a), (b), (c), 0, 0, 0)

// XCD-chunked block swizzle (nblk % 8 == 0): each XCD gets a contiguous chunk.
__device__ __forceinline__ int xcd_swizzle(int bid, int nblk) {
  const int per = nblk >> 3;
  return (bid & 7) * per + (bid >> 3);
}

__device__ __forceinline__ void gload_lds16(const bf16* g, bf16* lds) {
  __builtin_amdgcn_global_load_lds(
      (const __attribute__((address_space(1))) void*)g,
      (__attribute__((address_space(3))) void*)lds, 16, 0, 0);
}

// ---------------- GEMM: C[M,N] = (A[M,K] @ W[N,K]^T + bias) * cscale --------
// (unchanged from round 4 — 4 GEMMs + transpose measured ~88us)
template <typename T> struct StageRegs;
template <> struct StageRegs<float> { float4 lo[4], hi[4]; };
template <> struct StageRegs<bf16> { bf16x8 v[4]; };

template <typename T>
__device__ __forceinline__ void stage_issue(StageRegs<T>& r, const T* base,
                                            int rowstride, int brc, int k0,
                                            int tid) {
#pragma unroll
  for (int i = 0; i < 4; ++i) {
    const int c = i * 256 + tid;
    const int row = c >> 3, lin = c & 7;
    const T* p = base + (size_t)(brc + row) * rowstride + k0 + lin * 8;
    if constexpr (sizeof(T) == 4) {
      r.lo[i] = *reinterpret_cast<const float4*>(p);
      r.hi[i] = *reinterpret_cast<const float4*>(p + 4);
    } else {
      r.v[i] = *reinterpret_cast<const bf16x8*>(p);
    }
  }
}

template <typename T>
__device__ __forceinline__ void stage_write(const StageRegs<T>& r, bf16* sm,
                                            int tid) {
#pragma unroll
  for (int i = 0; i < 4; ++i) {
    const int c = i * 256 + tid;
    const int row = c >> 3, lin = c & 7;
    const int slot = lin ^ (row & 7);
    bf16x8 v;
    if constexpr (sizeof(T) == 4) {
      const float4 a = r.lo[i], b = r.hi[i];
      v[0] = (bf16)a.x; v[1] = (bf16)a.y; v[2] = (bf16)a.z; v[3] = (bf16)a.w;
      v[4] = (bf16)b.x; v[5] = (bf16)b.y; v[6] = (bf16)b.z; v[7] = (bf16)b.w;
    } else {
      v = r.v[i];
    }
    *reinterpret_cast<bf16x8*>(sm + row * 64 + slot * 8) = v;
  }
}

template <typename TA, typename TB, typename TC>
__global__ __launch_bounds__(256, 2) void gemm_bias_kernel(
    const TA* __restrict__ A, const TB* __restrict__ W,
    const float* __restrict__ bias, TC* __restrict__ C, int M, int N, int K,
    int nbc, float cscale) {
  __shared__ bf16 Asm[2][128 * 64];
  __shared__ bf16 Bsm[2][128 * 64];
  const int tid = threadIdx.x;
  const int lane = tid & 63;
  const int wid = tid >> 6;
  const int l15 = lane & 15;
  const int l4 = lane >> 4;
  const int bid = xcd_swizzle(blockIdx.x, gridDim.x);
  const int brow = (bid / nbc) << 7;
  const int bcol = (bid % nbc) << 7;
  const int wm = (wid >> 1) << 6;
  const int wn = (wid & 1) << 6;

  f32x4 acc[4][4] = {};

  StageRegs<TA> ra;
  StageRegs<TB> rb;
  stage_issue(ra, A, K, brow, 0, tid);
  stage_issue(rb, W, K, bcol, 0, tid);

  const int nt = K >> 6;
  int p = 0;
  for (int t = 0; t < nt; ++t) {
    stage_write(ra, Asm[p], tid);
    stage_write(rb, Bsm[p], tid);
    if (t + 1 < nt) {
      stage_issue(ra, A, K, brow, (t + 1) << 6, tid);
      stage_issue(rb, W, K, bcol, (t + 1) << 6, tid);
    }
    __syncthreads();
#pragma unroll
    for (int kk = 0; kk < 2; ++kk) {
      bf16x8 af[4], bfr[4];
#pragma unroll
      for (int m = 0; m < 4; ++m) {
        const int row = wm + m * 16 + l15;
        const int slot = (kk * 4 + l4) ^ (row & 7);
        af[m] = *reinterpret_cast<const bf16x8*>(Asm[p] + row * 64 + slot * 8);
      }
#pragma unroll
      for (int n = 0; n < 4; ++n) {
        const int row = wn + n * 16 + l15;
        const int slot = (kk * 4 + l4) ^ (row & 7);
        bfr[n] = *reinterpret_cast<const bf16x8*>(Bsm[p] + row * 64 + slot * 8);
      }
      __builtin_amdgcn_s_setprio(1);
#pragma unroll
      for (int m = 0; m < 4; ++m)
#pragma unroll
        for (int n = 0; n < 4; ++n)
          acc[m][n] = MFMA16(af[m], bfr[n], acc[m][n]);
      __builtin_amdgcn_s_setprio(0);
    }
    p ^= 1;
  }

  const int r0 = brow + wm + l4 * 4;
  const int c0 = bcol + wn + l15;
#pragma unroll
  for (int n = 0; n < 4; ++n) {
    const float bv = bias[c0 + n * 16];
#pragma unroll
    for (int m = 0; m < 4; ++m) {
#pragma unroll
      for (int r = 0; r < 4; ++r) {
        C[(size_t)(r0 + m * 16 + r) * N + (c0 + n * 16)] =
            (TC)((acc[m][n][r] + bv) * cscale);
      }
    }
  }
}

// Vt[(b*16+h)*64 + d][s] = V[(b*2048+s)*1024 + h*64 + d]   (bf16 -> bf16)
__global__ __launch_bounds__(256) void transpose_v_kernel(
    const bf16* __restrict__ V, bf16* __restrict__ Vt) {
  __shared__ unsigned short t[64][72];
  const int bid = blockIdx.x;
  const int st = bid & 31;
  const int h = (bid >> 5) & 15;
  const int b = bid >> 9;
  const int s0 = st * 64;
  const int tid = threadIdx.x;
#pragma unroll
  for (int i = 0; i < 2; ++i) {
    const int c = i * 256 + tid;
    const int row = c >> 3;
    const int off = (c & 7) * 8;
    const uint4 v = *reinterpret_cast<const uint4*>(
        &V[(size_t)(b * 2048 + s0 + row) * 1024 + h * 64 + off]);
    *reinterpret_cast<uint4*>(&t[row][off]) = v;
  }
  __syncthreads();
#pragma unroll
  for (int i = 0; i < 2; ++i) {
    const int c = i * 256 + tid;
    const int d = c >> 3;
    const int so = (c & 7) * 8;
    unsigned short tmp[8] __attribute__((aligned(16)));
#pragma unroll
    for (int j = 0; j < 8; ++j) tmp[j] = t[so + j][d];
    *reinterpret_cast<uint4*>(
        &Vt[(size_t)((b * 16 + h) * 64 + d) * 2048 + s0 + so]) =
        *reinterpret_cast<const uint4*>(tmp);
  }
}

// ---------------- Flash attention: swapped-QK^T softmax + defer-max --------
// Block = (b, h, 64 q-rows); 4 waves x 16 q-rows. K/Vt tiles LDS-staged,
// double-buffered (2-phase). QK^T computed TRANSPOSED: MFMA16(kf, qf) puts
// S[q][k] at lane(col=q=l15, row=k) -> each lane owns one q-row, 16 k-vals:
// row-reduce = 15 local fmax + 2 shfl (vs 32 shfl before). Online softmax
// state (mrow,lrow) lives at "home" lanes (q=l15, 4 copies); rescale of o
// (rows q=(l>>4)*4+r) redistributes alpha via 4 shfl ONLY on the rare tiles
// where max grows >8 (defer-max, T13).
__global__ __launch_bounds__(256, 4) void attn_kernel(
    const bf16* __restrict__ Q, const bf16* __restrict__ Kt,
    const bf16* __restrict__ Vt, const float* __restrict__ mask,
    bf16* __restrict__ ctx) {
  __shared__ bf16 Ksm[2][64 * 64];
  __shared__ bf16 Vsm[2][64 * 64];
  __shared__ bf16 Pl[4][1024];  // per-wave 16x64 P, 8B-slot XOR swizzle
  const int lid = xcd_swizzle(blockIdx.x, 2048);
  const int h = lid & 15;
  const int qb = (lid >> 4) & 31;
  const int b = lid >> 9;
  const int tid = threadIdx.x;
  const int lane = tid & 63;
  const int wid = tid >> 6;
  const int l15 = lane & 15;
  const int l4 = lane >> 4;

  const int qbase = qb * 64 + wid * 16;

  bf16x8 qf[2];
#pragma unroll
  for (int kk = 0; kk < 2; ++kk)
    qf[kk] = *reinterpret_cast<const bf16x8*>(
        &Q[(size_t)(b * 2048 + qbase + l15) * 1024 + h * 64 + kk * 32 + l4 * 8]);

  f32x4 o[4] = {};
  float mrow = -1e30f, lrow = 0.f;  // home layout: this lane's q = l15

  const float LOG2E = 1.44269504088896f;
  const bf16* Kb = Kt + (size_t)b * 2048 * 1024 + h * 64;
  const bf16* Vb = Vt + (size_t)(b * 16 + h) * 64 * 2048;
  const float* Mb = mask + (size_t)b * 2048 * 2048;
  char* Pw = reinterpret_cast<char*>(&Pl[wid][0]);
  const int qsw = (l15 & 7);  // P swizzle key for this lane's home row

  f32x4 mreg[4];  // [kt]: mask[qbase+l15][k0 + kt*16 + l4*4 + {0..3}]

  auto stage = [&](int p, int k0) {
#pragma unroll
    for (int i = 0; i < 2; ++i) {
      const int c = i * 256 + tid;
      const int row = c >> 3;
      const int lin = (c & 7) ^ (row & 7);
      gload_lds16(Kb + (size_t)(k0 + row) * 1024 + lin * 8, &Ksm[p][c * 8]);
      gload_lds16(Vb + (size_t)row * 2048 + k0 + lin * 8, &Vsm[p][c * 8]);
    }
  };
  auto load_mask = [&](int k0) {
#pragma unroll
    for (int kt = 0; kt < 4; ++kt)
      mreg[kt] = *reinterpret_cast<const f32x4*>(
          &Mb[(size_t)(qbase + l15) * 2048 + k0 + kt * 16 + l4 * 4]);
  };

  stage(0, 0);
  load_mask(0);
  asm volatile("s_waitcnt vmcnt(0)" ::: "memory");
  __syncthreads();

  int p = 0;
  for (int t = 0; t < 32; ++t) {
    const int k0 = t << 6;
    if (t + 1 < 32) stage(p ^ 1, k0 + 64);  // in flight during compute

    // S^T = (K Q^T): lane holds S[q=l15][k = k0 + kt*16 + l4*4 + r]
    f32x4 sf[4] = {};
    __builtin_amdgcn_s_setprio(1);
#pragma unroll
    for (int kt = 0; kt < 4; ++kt) {
#pragma unroll
      for (int kk = 0; kk < 2; ++kk) {
        const int row = kt * 16 + l15;
        const int slot = (kk * 4 + l4) ^ (row & 7);
        const bf16x8 kf =
            *reinterpret_cast<const bf16x8*>(&Ksm[p][row * 64 + slot * 8]);
        sf[kt] = MFMA16(kf, qf[kk], sf[kt]);
      }
    }
    __builtin_amdgcn_s_setprio(0);

    // mask add + local row max (this lane's 16 values of row q=l15)
    float rmax = -1e30f;
#pragma unroll
    for (int kt = 0; kt < 4; ++kt) {
#pragma unroll
      for (int r = 0; r < 4; ++r) {
        const float x = sf[kt][r] + mreg[kt][r];
        sf[kt][r] = x;
        rmax = fmaxf(rmax, x);
      }
    }
    if (t + 1 < 32) load_mask(k0 + 64);  // prefetch next mask

    // cross-lane max over the 4 home copies (lanes q, q+16, q+32, q+48)
    rmax = fmaxf(rmax, __shfl_xor(rmax, 16, 64));
    rmax = fmaxf(rmax, __shfl_xor(rmax, 32, 64));

    // defer-max: rescale only if some row's max grew by >8
    if (!__all(rmax <= mrow + 8.0f)) {
      const float mn = fmaxf(mrow, rmax);
      const float alpha = __builtin_exp2f((mrow - mn) * LOG2E);
      mrow = mn;
      lrow *= alpha;
      float ar[4];
#pragma unroll
      for (int r = 0; r < 4; ++r) ar[r] = __shfl(alpha, l4 * 4 + r, 64);
#pragma unroll
      for (int dt = 0; dt < 4; ++dt)
#pragma unroll
        for (int r = 0; r < 4; ++r) o[dt][r] *= ar[r];
    }

    // P = exp(S - mrow), bf16, packed 4-wide into swizzled LDS
    const float negmL = -mrow * LOG2E;
    float rsum = 0.f;
#pragma unroll
    for (int kt = 0; kt < 4; ++kt) {
      bf16x4 pk;
#pragma unroll
      for (int r = 0; r < 4; ++r) {
        const float pv = __builtin_exp2f(__builtin_fmaf(sf[kt][r], LOG2E, negmL));
        rsum += pv;
        pk[r] = (bf16)pv;
      }
      const int slot = (kt * 4 + l4) ^ qsw;
      *reinterpret_cast<bf16x4*>(Pw + l15 * 128 + slot * 8) = pk;
    }
    rsum += __shfl_xor(rsum, 16, 64);
    rsum += __shfl_xor(rsum, 32, 64);
    lrow += rsum;

    // O += P V  (P A-frag: row=l15=q, k = kk*32 + l4*8 + j -> 2 b64 per kk)
#pragma unroll
    for (int kk = 0; kk < 2; ++kk) {
      const int s0 = kk * 8 + l4 * 2;
      const bf16x4 plo =
          *reinterpret_cast<const bf16x4*>(Pw + l15 * 128 + (s0 ^ qsw) * 8);
      const bf16x4 phi =
          *reinterpret_cast<const bf16x4*>(Pw + l15 * 128 + ((s0 + 1) ^ qsw) * 8);
      bf16x8 pf;
#pragma unroll
      for (int j = 0; j < 4; ++j) { pf[j] = plo[j]; pf[j + 4] = phi[j]; }
      __builtin_amdgcn_s_setprio(1);
#pragma unroll
      for (int dt = 0; dt < 4; ++dt) {
        const int row = dt * 16 + l15;
        const int slot = (kk * 4 + l4) ^ (row & 7);
        const bf16x8 vf =
            *reinterpret_cast<const bf16x8*>(&Vsm[p][row * 64 + slot * 8]);
        o[dt] = MFMA16(pf, vf, o[dt]);
      }
      __builtin_amdgcn_s_setprio(0);
    }

    asm volatile("s_waitcnt vmcnt(0)" ::: "memory");
    __syncthreads();
    p ^= 1;
  }

  // redistribute lrow (home q=l15) to o-rows (q = l4*4 + r), then write
  float linv[4];
#pragma unroll
  for (int r = 0; r < 4; ++r)
    linv[r] = __builtin_amdgcn_rcpf(__shfl(lrow, l4 * 4 + r, 64));
#pragma unroll
  for (int dt = 0; dt < 4; ++dt) {
#pragma unroll
    for (int r = 0; r < 4; ++r) {
      const int q = qbase + l4 * 4 + r;
      ctx[(size_t)(b * 2048 + q) * 1024 + h * 64 + dt * 16 + l15] =
          (bf16)(o[dt][r] * linv[r]);
    }
  }
}

extern "C" void kernel_launch(void* const* d_in, const int* in_sizes, int n_in,
                              void* d_out, int out_size, void* d_ws,
                              size_t ws_size, hipStream_t stream) {
  const float* key = (const float*)d_in[0];
  const float* query = (const float*)d_in[1];
  const float* value = (const float*)d_in[2];
  const float* mask = (const float*)d_in[3];
  const float* wq = (const float*)d_in[4];
  const float* bq = (const float*)d_in[5];
  const float* wk = (const float*)d_in[6];
  const float* bk = (const float*)d_in[7];
  const float* wv = (const float*)d_in[8];
  const float* bv = (const float*)d_in[9];
  const float* wo = (const float*)d_in[10];
  const float* bo = (const float*)d_in[11];
  float* out = (float*)d_out;

  const size_t NBSH = (size_t)4 * 2048 * 1024;
  bf16* Qws = (bf16*)d_ws;   // Q (pre-scaled by 1/8), later ctx in place
  bf16* Kws = Qws + NBSH;
  bf16* Vt = Kws + NBSH;     // total ws use: 50.3 MB
  bf16* Vtmp = (bf16*)d_out; // stage bf16 V projection in d_out

  const dim3 blk(256);
  gemm_bias_kernel<float, float, bf16><<<512, blk, 0, stream>>>(
      query, wq, bq, Qws, 8192, 1024, 1024, 8, 0.125f);
  gemm_bias_kernel<float, float, bf16><<<512, blk, 0, stream>>>(
      key, wk, bk, Kws, 8192, 1024, 1024, 8, 1.0f);
  gemm_bias_kernel<float, float, bf16><<<512, blk, 0, stream>>>(
      value, wv, bv, Vtmp, 8192, 1024, 1024, 8, 1.0f);
  transpose_v_kernel<<<2048, blk, 0, stream>>>(Vtmp, Vt);
  attn_kernel<<<2048, blk, 0, stream>>>(Qws, Kws, Vt, mask, Qws);
  gemm_bias_kernel<bf16, float, float><<<512, blk, 0, stream>>>(
      Qws, wo, bo, out, 8192, 1024, 1024, 8, 1.0f);
}